// Round 3
// baseline (132.796 us; speedup 1.0000x reference)
//
#include <hip/hip_runtime.h>
#include <hip/hip_bf16.h>

// B=4, T=4096, E=512, H=64. out fp32 [B,T,H].
#define Bn 4
#define Tn 4096
#define En 512
#define Hn 64

typedef __attribute__((ext_vector_type(8))) __bf16 bf16x8;
typedef __attribute__((ext_vector_type(4))) __bf16 bf16x4;
typedef __attribute__((ext_vector_type(4))) float f32x4;

__device__ __forceinline__ unsigned short f2bf(float f) {
    union { float f; unsigned u; } v; v.f = f;
    unsigned r = v.u + 0x7fffu + ((v.u >> 16) & 1u);
    return (unsigned short)(r >> 16);
}

// ---------------- kernel 1: W fp32 -> bf16 concat [192][512] ----------------
__global__ void wcvt(const float* __restrict__ Wq, const float* __restrict__ Wk,
                     const float* __restrict__ Wv, unsigned short* __restrict__ Wo) {
    int i = blockIdx.x * 256 + threadIdx.x;      // 0..98303
    int mat = i >> 15;                            // each W is 64*512 = 32768
    int off = i & 32767;
    const float* s = (mat == 0) ? Wq : ((mat == 1) ? Wk : Wv);
    Wo[i] = f2bf(s[off]);
}

// ---------------- kernel 2: fused QKV projection (bf16 MFMA GEMM) -----------
// y = x @ Wqkv^T : M=16384 rows, N=192 cols, K=512.
// cols 0-63 -> q[row][h], 64-127 -> k[row][h], 128-191 -> v^T[b][h][t].
__launch_bounds__(256, 2)
__global__ void proj(const float* __restrict__ x, const unsigned short* __restrict__ Wo,
                     unsigned short* __restrict__ q16, unsigned short* __restrict__ k16,
                     unsigned short* __restrict__ vt16) {
    __shared__ unsigned short sA[64 * 72];   // 64 rows x 64 k, stride 72 (pad kills bank conflict)
    __shared__ unsigned short sW[192 * 72];
    const int tid = threadIdx.x;
    const int w = tid >> 6, lane = tid & 63, r = lane & 15, g = lane >> 4;
    const int row0 = blockIdx.x * 64;

    f32x4 acc[12];
#pragma unroll
    for (int i = 0; i < 12; ++i) acc[i] = (f32x4){0.f, 0.f, 0.f, 0.f};

    for (int k0 = 0; k0 < En; k0 += 64) {
        // stage A: 64x64 fp32 -> bf16 (chunks of 8)
#pragma unroll
        for (int i = 0; i < 2; ++i) {
            int c = tid + i * 256; int arow = c >> 3, kc = (c & 7) * 8;
            const float4* xp = (const float4*)&x[(row0 + arow) * En + k0 + kc];
            float4 f0 = xp[0], f1 = xp[1];
            union { bf16x8 v; unsigned short u[8]; } t;
            t.u[0] = f2bf(f0.x); t.u[1] = f2bf(f0.y); t.u[2] = f2bf(f0.z); t.u[3] = f2bf(f0.w);
            t.u[4] = f2bf(f1.x); t.u[5] = f2bf(f1.y); t.u[6] = f2bf(f1.z); t.u[7] = f2bf(f1.w);
            *(bf16x8*)&sA[arow * 72 + kc] = t.v;
        }
        // stage W: 192x64 bf16
#pragma unroll
        for (int i = 0; i < 6; ++i) {
            int c = tid + i * 256; int wrow = c >> 3, kc = (c & 7) * 8;
            bf16x8 wv = *(const bf16x8*)&Wo[wrow * En + k0 + kc];
            *(bf16x8*)&sW[wrow * 72 + kc] = wv;
        }
        __syncthreads();
        bf16x8 a0 = *(bf16x8*)&sA[(w * 16 + r) * 72 + g * 8];
        bf16x8 a1 = *(bf16x8*)&sA[(w * 16 + r) * 72 + 32 + g * 8];
#pragma unroll
        for (int ct = 0; ct < 12; ++ct) {
            bf16x8 b0 = *(bf16x8*)&sW[(ct * 16 + r) * 72 + g * 8];
            bf16x8 b1 = *(bf16x8*)&sW[(ct * 16 + r) * 72 + 32 + g * 8];
            acc[ct] = __builtin_amdgcn_mfma_f32_16x16x32_bf16(a0, b0, acc[ct], 0, 0, 0);
            acc[ct] = __builtin_amdgcn_mfma_f32_16x16x32_bf16(a1, b1, acc[ct], 0, 0, 0);
        }
        __syncthreads();
    }
    // epilogue: C layout col = lane&15, row = (lane>>4)*4 + reg  (m89-verified)
#pragma unroll
    for (int ct = 0; ct < 12; ++ct) {
        int n = ct * 16 + r;
#pragma unroll
        for (int reg = 0; reg < 4; ++reg) {
            int gr = row0 + w * 16 + g * 4 + reg;
            unsigned short bv = f2bf(acc[ct][reg]);
            if (n < 64) {
                q16[gr * 64 + n] = bv;
            } else if (n < 128) {
                k16[gr * 64 + (n - 64)] = bv;
            } else {
                int h = n - 128; int bb = gr >> 12; int t = gr & 4095;
                vt16[((bb * 64 + h) << 12) + t] = bv;
            }
        }
    }
}

// ---------------- kernel 3: causal flash attention ---------------------------
// 1024 blocks x 4 waves. Block = one 16-row q tile; waves split KV (kb ≡ w mod 4),
// merge partial (m,l,o) through LDS at the end.
// Swapped QK^T: S^T = mfma(K, Q), so lane owns one q-row (q = lane&15) with
// kv along regs -> softmax is in-lane + 2 shuffles; P feeds PV's A-frag from
// registers with the k-bijection (g,j) -> g*4+(j&3)+16*(j>>2) mirrored in the
// V B-frag loads. No LDS in the main loop.
__launch_bounds__(256, 4)
__global__ void attn(const unsigned short* __restrict__ q16, const unsigned short* __restrict__ k16,
                     const unsigned short* __restrict__ vt16, float* __restrict__ out) {
    __shared__ float oM[4][16][64];
    __shared__ float mM[4][16];
    __shared__ float lM[4][16];

    const int tid = threadIdx.x;
    const int w = tid >> 6, lane = tid & 63, r = lane & 15, g = lane >> 4;
    const int bid = blockIdx.x;
    const int b = (bid >> 1) & 3;                          // batch -> XCD pair (L2 locality)
    const int i16 = 255 - (((bid >> 3) << 1) | (bid & 1)); // longest tiles first
    const int q0 = i16 * 16;
    const int qrow = b * Tn + q0;

    // Q as B-fragment: col = r (q index), k-slots = d = g*8..g*8+7 (+32)
    const bf16x8 bq0 = *(const bf16x8*)&q16[(qrow + r) * 64 + g * 8];
    const bf16x8 bq1 = *(const bf16x8*)&q16[(qrow + r) * 64 + 32 + g * 8];

    f32x4 o[4];
#pragma unroll
    for (int i = 0; i < 4; ++i) o[i] = (f32x4){0.f, 0.f, 0.f, 0.f};
    float m_ = -1e30f, l_ = 0.f;

    const int kbmax = i16 >> 2;
    const float scale = 0.125f;   // 1/sqrt(64)
    const int q = q0 + r;
    const unsigned short* vbase = &vt16[(size_t)(b * 64) << 12];

    for (int kb = w; kb <= kbmax; kb += 4) {
        const int kv0 = kb * 64;
        // S^T tile: rows = kv (g*4+reg per 16-tile), cols = q (r)
        f32x4 s[4];
#pragma unroll
        for (int ct = 0; ct < 4; ++ct) {
            const unsigned short* kp = &k16[(b * Tn + kv0 + ct * 16 + r) * 64 + g * 8];
            bf16x8 ak0 = *(const bf16x8*)kp;
            bf16x8 ak1 = *(const bf16x8*)(kp + 32);
            f32x4 t = (f32x4){0.f, 0.f, 0.f, 0.f};
            t = __builtin_amdgcn_mfma_f32_16x16x32_bf16(ak0, bq0, t, 0, 0, 0);
            t = __builtin_amdgcn_mfma_f32_16x16x32_bf16(ak1, bq1, t, 0, 0, 0);
            s[ct] = t;
        }
        if (kb == kbmax) {
#pragma unroll
            for (int ct = 0; ct < 4; ++ct)
#pragma unroll
                for (int reg = 0; reg < 4; ++reg) {
                    int kv = kv0 + ct * 16 + g * 4 + reg;
                    s[ct][reg] = (kv > q) ? -1e30f : s[ct][reg] * scale;
                }
        } else {
#pragma unroll
            for (int ct = 0; ct < 4; ++ct)
#pragma unroll
                for (int reg = 0; reg < 4; ++reg) s[ct][reg] *= scale;
        }
        // row max over 64 kv for this lane's q: in-lane tree + 2 shuffles
        float a0 = fmaxf(fmaxf(s[0][0], s[0][1]), fmaxf(s[0][2], s[0][3]));
        float a1 = fmaxf(fmaxf(s[1][0], s[1][1]), fmaxf(s[1][2], s[1][3]));
        float a2 = fmaxf(fmaxf(s[2][0], s[2][1]), fmaxf(s[2][2], s[2][3]));
        float a3 = fmaxf(fmaxf(s[3][0], s[3][1]), fmaxf(s[3][2], s[3][3]));
        float mx = fmaxf(fmaxf(a0, a1), fmaxf(a2, a3));
        mx = fmaxf(mx, __shfl_xor(mx, 16));
        mx = fmaxf(mx, __shfl_xor(mx, 32));

        float mn = fmaxf(m_, mx);
        float corr = __expf(m_ - mn);
        m_ = mn;
#pragma unroll
        for (int ct = 0; ct < 4; ++ct)
#pragma unroll
            for (int reg = 0; reg < 4; ++reg)
                s[ct][reg] = __expf(s[ct][reg] - mn);
        float b0s = (s[0][0] + s[0][1]) + (s[0][2] + s[0][3]);
        float b1s = (s[1][0] + s[1][1]) + (s[1][2] + s[1][3]);
        float b2s = (s[2][0] + s[2][1]) + (s[2][2] + s[2][3]);
        float b3s = (s[3][0] + s[3][1]) + (s[3][2] + s[3][3]);
        float sm = (b0s + b1s) + (b2s + b3s);
        sm += __shfl_xor(sm, 16);
        sm += __shfl_xor(sm, 32);
        l_ = l_ * corr + sm;

        // rescale O (its rows are q = g*4+reg -> broadcast corr from lane g*4+reg)
        float cq[4];
#pragma unroll
        for (int reg = 0; reg < 4; ++reg) cq[reg] = __shfl(corr, g * 4 + reg);
#pragma unroll
        for (int cth = 0; cth < 4; ++cth)
#pragma unroll
            for (int reg = 0; reg < 4; ++reg) o[cth][reg] *= cq[reg];

        // pack P as A-frag: slot j -> kv-local = (j>>2)*16 + g*4 + (j&3)
        union { bf16x8 v; unsigned short u[8]; } p0, p1;
#pragma unroll
        for (int j = 0; j < 4; ++j) {
            p0.u[j]     = f2bf(s[0][j]);
            p0.u[4 + j] = f2bf(s[1][j]);
            p1.u[j]     = f2bf(s[2][j]);
            p1.u[4 + j] = f2bf(s[3][j]);
        }
        // PV: B-frag of V with matching k-bijection; V^T rows are h
#pragma unroll
        for (int cth = 0; cth < 4; ++cth) {
            const unsigned short* vp = vbase + (((size_t)(cth * 16 + r)) << 12) + kv0 + g * 4;
            union { bf16x8 v; bf16x4 h[2]; } v0, v1;
            v0.h[0] = *(const bf16x4*)(vp);
            v0.h[1] = *(const bf16x4*)(vp + 16);
            v1.h[0] = *(const bf16x4*)(vp + 32);
            v1.h[1] = *(const bf16x4*)(vp + 48);
            o[cth] = __builtin_amdgcn_mfma_f32_16x16x32_bf16(p0.v, v0.v, o[cth], 0, 0, 0);
            o[cth] = __builtin_amdgcn_mfma_f32_16x16x32_bf16(p1.v, v1.v, o[cth], 0, 0, 0);
        }
    }

    // ---- write per-wave partials to LDS (O rows are q = g*4+reg) ----
#pragma unroll
    for (int cth = 0; cth < 4; ++cth)
#pragma unroll
        for (int reg = 0; reg < 4; ++reg)
            oM[w][g * 4 + reg][cth * 16 + r] = o[cth][reg];
    if (lane < 16) {
        mM[w][lane] = m_;
        lM[w][lane] = l_;
    }
    __syncthreads();

    // ---- merge: wave w handles rows w*4 + g; lane r covers cols r+16j ----
    {
        int rr = w * 4 + g;
        float m0 = mM[0][rr], m1 = mM[1][rr], m2 = mM[2][rr], m3 = mM[3][rr];
        float M = fmaxf(fmaxf(m0, m1), fmaxf(m2, m3));
        float w0 = __expf(m0 - M), w1 = __expf(m1 - M), w2 = __expf(m2 - M), w3 = __expf(m3 - M);
        float L = w0 * lM[0][rr] + w1 * lM[1][rr] + w2 * lM[2][rr] + w3 * lM[3][rr];
        float inv = 1.0f / L;
        int orow = b * Tn + q0 + rr;
#pragma unroll
        for (int j = 0; j < 4; ++j) {
            int col = r + 16 * j;
            float val = w0 * oM[0][rr][col] + w1 * oM[1][rr][col] +
                        w2 * oM[2][rr][col] + w3 * oM[3][rr][col];
            out[orow * 64 + col] = val * inv;
        }
    }
}

extern "C" void kernel_launch(void* const* d_in, const int* in_sizes, int n_in,
                              void* d_out, int out_size, void* d_ws, size_t ws_size,
                              hipStream_t stream) {
    const float* x  = (const float*)d_in[0];
    const float* Wq = (const float*)d_in[1];
    const float* Wk = (const float*)d_in[2];
    const float* Wv = (const float*)d_in[3];
    float* out = (float*)d_out;
    char* ws = (char*)d_ws;

    unsigned short* Wo  = (unsigned short*)ws;                       // 192*512*2   = 196608 B
    unsigned short* q16 = (unsigned short*)(ws + 196608);            // 16384*64*2  = 2 MiB
    unsigned short* k16 = (unsigned short*)(ws + 196608 + 2097152);
    unsigned short* v16 = (unsigned short*)(ws + 196608 + 2 * 2097152);
    // total ws use: ~6.2 MiB

    hipLaunchKernelGGL(wcvt, dim3(384), dim3(256), 0, stream, Wq, Wk, Wv, Wo);
    hipLaunchKernelGGL(proj, dim3(256), dim3(256), 0, stream, x, Wo, q16, k16, v16);
    hipLaunchKernelGGL(attn, dim3(1024), dim3(256), 0, stream, q16, k16, v16, out);
}

// Round 4
// 73.615 us; speedup vs baseline: 1.8039x; 1.8039x over previous
//
#include <hip/hip_runtime.h>
#include <hip/hip_bf16.h>

// B=4, T=4096, E=512, H=64. out fp32 [B,T,H].
#define Bn 4
#define Tn 4096
#define En 512
#define Hn 64
#define NEGINF -3e38f

typedef __attribute__((ext_vector_type(8))) __bf16 bf16x8;
typedef __attribute__((ext_vector_type(4))) __bf16 bf16x4;
typedef __attribute__((ext_vector_type(4))) float f32x4;

#define MFMA16(a, b, c) __builtin_amdgcn_mfma_f32_16x16x32_bf16(a, b, c, 0, 0, 0)

__device__ __forceinline__ unsigned short f2bf(float f) {
    union { float f; unsigned u; } v; v.f = f;
    unsigned r = v.u + 0x7fffu + ((v.u >> 16) & 1u);
    return (unsigned short)(r >> 16);
}

// ---------------- kernel 1: W fp32 -> bf16 concat [192][512] ----------------
__global__ void wcvt(const float* __restrict__ Wq, const float* __restrict__ Wk,
                     const float* __restrict__ Wv, unsigned short* __restrict__ Wo) {
    int i = blockIdx.x * 256 + threadIdx.x;      // 0..98303
    int mat = i >> 15;                            // each W is 64*512 = 32768
    int off = i & 32767;
    const float* s = (mat == 0) ? Wq : ((mat == 1) ? Wk : Wv);
    Wo[i] = f2bf(s[off]);
}

// ---------------- kernel 2: fused QKV projection (bf16 MFMA GEMM) -----------
// y = x @ Wqkv^T : M=16384 rows, N=192 cols, K=512.
// cols 0-63 -> q[row][h], 64-127 -> k[row][h], 128-191 -> v^T[b][h][t].
__launch_bounds__(256, 2)
__global__ void proj(const float* __restrict__ x, const unsigned short* __restrict__ Wo,
                     unsigned short* __restrict__ q16, unsigned short* __restrict__ k16,
                     unsigned short* __restrict__ vt16) {
    __shared__ unsigned short sA[64 * 72];   // 64 rows x 64 k, stride 72 (pad kills bank conflict)
    __shared__ unsigned short sW[192 * 72];
    const int tid = threadIdx.x;
    const int w = tid >> 6, lane = tid & 63, r = lane & 15, g = lane >> 4;
    const int row0 = blockIdx.x * 64;

    f32x4 acc[12];
#pragma unroll
    for (int i = 0; i < 12; ++i) acc[i] = (f32x4){0.f, 0.f, 0.f, 0.f};

    for (int k0 = 0; k0 < En; k0 += 64) {
#pragma unroll
        for (int i = 0; i < 2; ++i) {
            int c = tid + i * 256; int arow = c >> 3, kc = (c & 7) * 8;
            const float4* xp = (const float4*)&x[(row0 + arow) * En + k0 + kc];
            float4 f0 = xp[0], f1 = xp[1];
            union { bf16x8 v; unsigned short u[8]; } t;
            t.u[0] = f2bf(f0.x); t.u[1] = f2bf(f0.y); t.u[2] = f2bf(f0.z); t.u[3] = f2bf(f0.w);
            t.u[4] = f2bf(f1.x); t.u[5] = f2bf(f1.y); t.u[6] = f2bf(f1.z); t.u[7] = f2bf(f1.w);
            *(bf16x8*)&sA[arow * 72 + kc] = t.v;
        }
#pragma unroll
        for (int i = 0; i < 6; ++i) {
            int c = tid + i * 256; int wrow = c >> 3, kc = (c & 7) * 8;
            bf16x8 wv = *(const bf16x8*)&Wo[wrow * En + k0 + kc];
            *(bf16x8*)&sW[wrow * 72 + kc] = wv;
        }
        __syncthreads();
        bf16x8 a0 = *(bf16x8*)&sA[(w * 16 + r) * 72 + g * 8];
        bf16x8 a1 = *(bf16x8*)&sA[(w * 16 + r) * 72 + 32 + g * 8];
#pragma unroll
        for (int ct = 0; ct < 12; ++ct) {
            bf16x8 b0 = *(bf16x8*)&sW[(ct * 16 + r) * 72 + g * 8];
            bf16x8 b1 = *(bf16x8*)&sW[(ct * 16 + r) * 72 + 32 + g * 8];
            acc[ct] = MFMA16(a0, b0, acc[ct]);
            acc[ct] = MFMA16(a1, b1, acc[ct]);
        }
        __syncthreads();
    }
#pragma unroll
    for (int ct = 0; ct < 12; ++ct) {
        int n = ct * 16 + r;
#pragma unroll
        for (int reg = 0; reg < 4; ++reg) {
            int gr = row0 + w * 16 + g * 4 + reg;
            unsigned short bv = f2bf(acc[ct][reg]);
            if (n < 64) {
                q16[gr * 64 + n] = bv;
            } else if (n < 128) {
                k16[gr * 64 + (n - 64)] = bv;
            } else {
                int h = n - 128; int bb = gr >> 12; int t = gr & 4095;
                vt16[((bb * 64 + h) << 12) + t] = bv;
            }
        }
    }
}

// ---------------- kernel 3: causal flash attention (LDS-staged) --------------
// 256 blocks x 512 threads (8 waves = 2 q-subtiles x 4-way KV split).
// Block = paired q-tiles (127-p, p) of 32 rows -> uniform ~33 iters/block.
// Per iter: stage 128-kv K (16KB) + V^T (16KB) tiles into dbuf LDS
// (XOR-swizzle (row&7)<<4), swapped-QK^T in-register softmax, PV from LDS.
__launch_bounds__(512, 2)
__global__ void attn(const unsigned short* __restrict__ q16, const unsigned short* __restrict__ k16,
                     const unsigned short* __restrict__ vt16, float* __restrict__ out) {
    __shared__ __align__(16) unsigned char lds[2][32768];  // [buf][K 16KB | V 16KB]
    __shared__ float oM[2][4][16][64];
    __shared__ float mM[2][4][16], lM[2][4][16];

    const int tid = threadIdx.x;
    const int w = tid >> 6, lane = tid & 63, r = lane & 15, g = lane >> 4;
    const int sq = w >> 2, sk = w & 3;
    const int bid = blockIdx.x;
    const int b = (bid >> 1) & 3;                          // batch -> XCD pair
    const int pairIdx = ((bid >> 3) << 1) | (bid & 1);     // 0..63
    const size_t kbase = (size_t)b * Tn;
    const float scale = 0.125f;

    for (int tt = 0; tt < 2; ++tt) {
        const int j = (tt == 0) ? (127 - pairIdx) : pairIdx;
        const int q0 = j * 32;
        const int nIt = (j + 4) >> 2;                      // ceil(32(j+1)/128)
        const int qrow = b * Tn + q0 + sq * 16;
        const int q = q0 + sq * 16 + r;
        const int qmax = q0 + sq * 16 + 15;

        const bf16x8 bq0 = *(const bf16x8*)&q16[(qrow + r) * 64 + g * 8];
        const bf16x8 bq1 = *(const bf16x8*)&q16[(qrow + r) * 64 + 32 + g * 8];

        f32x4 o[4];
#pragma unroll
        for (int i = 0; i < 4; ++i) o[i] = (f32x4){0.f, 0.f, 0.f, 0.f};
        float m_ = -1e30f, l_ = 0.f;

        // prologue: stage kv tile 0 into buf 0
        {
#pragma unroll
            for (int p = 0; p < 2; ++p) {
                int row = p * 64 + (tid >> 3), cb = (tid & 7) * 16;
                bf16x8 t = *(const bf16x8*)((const char*)k16 + (kbase + row) * 128 + cb);
                *(bf16x8*)&lds[0][row * 128 + (cb ^ ((row & 7) << 4))] = t;
            }
#pragma unroll
            for (int p = 0; p < 2; ++p) {
                int h = p * 32 + (tid >> 4), cb = (tid & 15) * 16;
                bf16x8 t = *(const bf16x8*)((const char*)vt16 + ((size_t)(b * 64 + h)) * 8192 + cb);
                *(bf16x8*)&lds[0][16384 + h * 256 + (cb ^ ((h & 7) << 4))] = t;
            }
        }
        __syncthreads();

        for (int it = 0; it < nIt; ++it) {
            const int pp = it & 1;
            const int kv0 = it * 128;
            const bool more = (it + 1 < nIt);
            // T14: issue next-stage global loads early
            bf16x8 sK0, sK1, sV0, sV1;
            int dK0 = 0, dK1 = 0, dV0 = 0, dV1 = 0;
            if (more) {
                int nkv = kv0 + 128;
                int row0_ = (tid >> 3), cb = (tid & 7) * 16;
                sK0 = *(const bf16x8*)((const char*)k16 + (kbase + nkv + row0_) * 128 + cb);
                dK0 = row0_ * 128 + (cb ^ ((row0_ & 7) << 4));
                int row1_ = 64 + row0_;
                sK1 = *(const bf16x8*)((const char*)k16 + (kbase + nkv + row1_) * 128 + cb);
                dK1 = row1_ * 128 + (cb ^ ((row1_ & 7) << 4));
                int h0 = (tid >> 4), cv = (tid & 15) * 16;
                sV0 = *(const bf16x8*)((const char*)vt16 + ((size_t)(b * 64 + h0)) * 8192 + nkv * 2 + cv);
                dV0 = 16384 + h0 * 256 + (cv ^ ((h0 & 7) << 4));
                int h1 = 32 + h0;
                sV1 = *(const bf16x8*)((const char*)vt16 + ((size_t)(b * 64 + h1)) * 8192 + nkv * 2 + cv);
                dV1 = 16384 + h1 * 256 + (cv ^ ((h1 & 7) << 4));
            }
            // compute on buf pp (wave-uniform causal skip; barriers stay outside)
            if (kv0 + sk * 32 <= qmax) {
                const unsigned char* K = &lds[pp][0];
                const unsigned char* V = &lds[pp][16384];
                f32x4 s[2];
#pragma unroll
                for (int ct = 0; ct < 2; ++ct) {
                    int row = sk * 32 + ct * 16 + r;
                    int base = row * 128, sw = (row & 7) << 4;
                    bf16x8 ak0 = *(const bf16x8*)&K[base + ((g * 16) ^ sw)];
                    bf16x8 ak1 = *(const bf16x8*)&K[base + ((64 + g * 16) ^ sw)];
                    f32x4 t = (f32x4){0.f, 0.f, 0.f, 0.f};
                    t = MFMA16(ak0, bq0, t);
                    t = MFMA16(ak1, bq1, t);
                    s[ct] = t;
                }
#pragma unroll
                for (int ct = 0; ct < 2; ++ct)
#pragma unroll
                    for (int reg = 0; reg < 4; ++reg) {
                        int kv = kv0 + sk * 32 + ct * 16 + g * 4 + reg;
                        s[ct][reg] = (kv > q) ? NEGINF : s[ct][reg] * scale;
                    }
                // softmax over this 32-kv window (lane owns q-row r)
                float mx = fmaxf(fmaxf(fmaxf(s[0][0], s[0][1]), fmaxf(s[0][2], s[0][3])),
                                 fmaxf(fmaxf(s[1][0], s[1][1]), fmaxf(s[1][2], s[1][3])));
                mx = fmaxf(mx, __shfl_xor(mx, 16));
                mx = fmaxf(mx, __shfl_xor(mx, 32));
                float mn = fmaxf(m_, mx);
                float corr = __expf(m_ - mn);
                m_ = mn;
#pragma unroll
                for (int ct = 0; ct < 2; ++ct)
#pragma unroll
                    for (int reg = 0; reg < 4; ++reg)
                        s[ct][reg] = __expf(s[ct][reg] - mn);
                float sm = ((s[0][0] + s[0][1]) + (s[0][2] + s[0][3])) +
                           ((s[1][0] + s[1][1]) + (s[1][2] + s[1][3]));
                sm += __shfl_xor(sm, 16);
                sm += __shfl_xor(sm, 32);
                l_ = l_ * corr + sm;
                float cq[4];
#pragma unroll
                for (int reg = 0; reg < 4; ++reg) cq[reg] = __shfl(corr, g * 4 + reg);
#pragma unroll
                for (int cth = 0; cth < 4; ++cth)
#pragma unroll
                    for (int reg = 0; reg < 4; ++reg) o[cth][reg] *= cq[reg];
                // pack P: A-slot j -> window-kv = (j>>2)*16 + g*4 + (j&3)
                union { bf16x8 v; unsigned short u[8]; } pk;
#pragma unroll
                for (int jj = 0; jj < 4; ++jj) {
                    pk.u[jj] = f2bf(s[0][jj]);
                    pk.u[4 + jj] = f2bf(s[1][jj]);
                }
                // PV: V B-frag with same bijection, conflict-free swizzled reads
#pragma unroll
                for (int cth = 0; cth < 4; ++cth) {
                    int h = cth * 16 + r;
                    int vb = h * 256, sw = (h & 7) << 4;
                    union { bf16x8 v; bf16x4 h4[2]; } vv;
                    vv.h4[0] = *(const bf16x4*)&V[vb + ((sk * 64 + g * 8) ^ sw)];
                    vv.h4[1] = *(const bf16x4*)&V[vb + ((sk * 64 + 32 + g * 8) ^ sw)];
                    o[cth] = MFMA16(pk.v, vv.v, o[cth]);
                }
            }
            if (more) {
                unsigned char* D = &lds[pp ^ 1][0];
                *(bf16x8*)&D[dK0] = sK0;
                *(bf16x8*)&D[dK1] = sK1;
                *(bf16x8*)&D[dV0] = sV0;
                *(bf16x8*)&D[dV1] = sV1;
            }
            __syncthreads();
        }

        // ---- partials to LDS ----
#pragma unroll
        for (int cth = 0; cth < 4; ++cth)
#pragma unroll
            for (int reg = 0; reg < 4; ++reg)
                oM[sq][sk][g * 4 + reg][cth * 16 + r] = o[cth][reg];
        if (lane < 16) {
            mM[sq][sk][lane] = m_;
            lM[sq][sk][lane] = l_;
        }
        __syncthreads();

        // ---- merge 4-way across sk; wave (sq,sk) takes rows sk*4+g ----
        {
            int rr = sk * 4 + g;
            float m0 = mM[sq][0][rr], m1 = mM[sq][1][rr], m2 = mM[sq][2][rr], m3 = mM[sq][3][rr];
            float M = fmaxf(fmaxf(m0, m1), fmaxf(m2, m3));
            float w0 = __expf(m0 - M), w1 = __expf(m1 - M), w2 = __expf(m2 - M), w3 = __expf(m3 - M);
            float L = w0 * lM[sq][0][rr] + w1 * lM[sq][1][rr] + w2 * lM[sq][2][rr] + w3 * lM[sq][3][rr];
            float inv = 1.0f / L;
            int orow = b * Tn + q0 + sq * 16 + rr;
#pragma unroll
            for (int jj = 0; jj < 4; ++jj) {
                int col = r + 16 * jj;
                float val = w0 * oM[sq][0][rr][col] + w1 * oM[sq][1][rr][col] +
                            w2 * oM[sq][2][rr][col] + w3 * oM[sq][3][rr][col];
                out[orow * 64 + col] = val * inv;
            }
        }
        // no extra barrier needed: next tile's first oM write is separated by
        // its prologue + loop barriers from this tile's merge reads.
    }
}

extern "C" void kernel_launch(void* const* d_in, const int* in_sizes, int n_in,
                              void* d_out, int out_size, void* d_ws, size_t ws_size,
                              hipStream_t stream) {
    const float* x  = (const float*)d_in[0];
    const float* Wq = (const float*)d_in[1];
    const float* Wk = (const float*)d_in[2];
    const float* Wv = (const float*)d_in[3];
    float* out = (float*)d_out;
    char* ws = (char*)d_ws;

    unsigned short* Wo  = (unsigned short*)ws;                       // 192*512*2   = 196608 B
    unsigned short* q16 = (unsigned short*)(ws + 196608);            // 16384*64*2  = 2 MiB
    unsigned short* k16 = (unsigned short*)(ws + 196608 + 2097152);
    unsigned short* v16 = (unsigned short*)(ws + 196608 + 2 * 2097152);

    hipLaunchKernelGGL(wcvt, dim3(384), dim3(256), 0, stream, Wq, Wk, Wv, Wo);
    hipLaunchKernelGGL(proj, dim3(256), dim3(256), 0, stream, x, Wo, q16, k16, v16);
    hipLaunchKernelGGL(attn, dim3(256), dim3(512), 0, stream, q16, k16, v16, out);
}

// Round 5
// 72.815 us; speedup vs baseline: 1.8237x; 1.0110x over previous
//
#include <hip/hip_runtime.h>
#include <hip/hip_bf16.h>

// B=4, T=4096, E=512, H=64. out fp32 [B,T,H].
#define Bn 4
#define Tn 4096
#define En 512
#define Hn 64
#define NEGINF -3e38f

typedef __attribute__((ext_vector_type(8))) __bf16 bf16x8;
typedef __attribute__((ext_vector_type(4))) __bf16 bf16x4;
typedef __attribute__((ext_vector_type(4))) float f32x4;

#define MFMA16(a, b, c) __builtin_amdgcn_mfma_f32_16x16x32_bf16(a, b, c, 0, 0, 0)

__device__ __forceinline__ unsigned short f2bf(float f) {
    union { float f; unsigned u; } v; v.f = f;
    unsigned r = v.u + 0x7fffu + ((v.u >> 16) & 1u);
    return (unsigned short)(r >> 16);
}

// ---------------- kernel 1: W fp32 -> bf16 concat [192][512] ----------------
__global__ void wcvt(const float* __restrict__ Wq, const float* __restrict__ Wk,
                     const float* __restrict__ Wv, unsigned short* __restrict__ Wo) {
    int i = blockIdx.x * 256 + threadIdx.x;      // 0..98303
    int mat = i >> 15;                            // each W is 64*512 = 32768
    int off = i & 32767;
    const float* s = (mat == 0) ? Wq : ((mat == 1) ? Wk : Wv);
    Wo[i] = f2bf(s[off]);
}

// ---------------- kernel 2: fused QKV projection (bf16 MFMA GEMM) -----------
// y = x @ Wqkv^T : M=16384 rows, N=192 cols, K=512.
// cols 0-63 -> q[row][h], 64-127 -> k[row][h], 128-191 -> v^T[b][h][t].
__launch_bounds__(256, 2)
__global__ void proj(const float* __restrict__ x, const unsigned short* __restrict__ Wo,
                     unsigned short* __restrict__ q16, unsigned short* __restrict__ k16,
                     unsigned short* __restrict__ vt16) {
    __shared__ unsigned short sA[64 * 72];   // 64 rows x 64 k, stride 72 (pad kills bank conflict)
    __shared__ unsigned short sW[192 * 72];
    const int tid = threadIdx.x;
    const int w = tid >> 6, lane = tid & 63, r = lane & 15, g = lane >> 4;
    const int row0 = blockIdx.x * 64;

    f32x4 acc[12];
#pragma unroll
    for (int i = 0; i < 12; ++i) acc[i] = (f32x4){0.f, 0.f, 0.f, 0.f};

    for (int k0 = 0; k0 < En; k0 += 64) {
#pragma unroll
        for (int i = 0; i < 2; ++i) {
            int c = tid + i * 256; int arow = c >> 3, kc = (c & 7) * 8;
            const float4* xp = (const float4*)&x[(row0 + arow) * En + k0 + kc];
            float4 f0 = xp[0], f1 = xp[1];
            union { bf16x8 v; unsigned short u[8]; } t;
            t.u[0] = f2bf(f0.x); t.u[1] = f2bf(f0.y); t.u[2] = f2bf(f0.z); t.u[3] = f2bf(f0.w);
            t.u[4] = f2bf(f1.x); t.u[5] = f2bf(f1.y); t.u[6] = f2bf(f1.z); t.u[7] = f2bf(f1.w);
            *(bf16x8*)&sA[arow * 72 + kc] = t.v;
        }
#pragma unroll
        for (int i = 0; i < 6; ++i) {
            int c = tid + i * 256; int wrow = c >> 3, kc = (c & 7) * 8;
            bf16x8 wv = *(const bf16x8*)&Wo[wrow * En + k0 + kc];
            *(bf16x8*)&sW[wrow * 72 + kc] = wv;
        }
        __syncthreads();
        bf16x8 a0 = *(bf16x8*)&sA[(w * 16 + r) * 72 + g * 8];
        bf16x8 a1 = *(bf16x8*)&sA[(w * 16 + r) * 72 + 32 + g * 8];
#pragma unroll
        for (int ct = 0; ct < 12; ++ct) {
            bf16x8 b0 = *(bf16x8*)&sW[(ct * 16 + r) * 72 + g * 8];
            bf16x8 b1 = *(bf16x8*)&sW[(ct * 16 + r) * 72 + 32 + g * 8];
            acc[ct] = MFMA16(a0, b0, acc[ct]);
            acc[ct] = MFMA16(a1, b1, acc[ct]);
        }
        __syncthreads();
    }
#pragma unroll
    for (int ct = 0; ct < 12; ++ct) {
        int n = ct * 16 + r;
#pragma unroll
        for (int reg = 0; reg < 4; ++reg) {
            int gr = row0 + w * 16 + g * 4 + reg;
            unsigned short bv = f2bf(acc[ct][reg]);
            if (n < 64) {
                q16[gr * 64 + n] = bv;
            } else if (n < 128) {
                k16[gr * 64 + (n - 64)] = bv;
            } else {
                int h = n - 128; int bb = gr >> 12; int t = gr & 4095;
                vt16[((bb * 64 + h) << 12) + t] = bv;
            }
        }
    }
}

// ---------------- kernel 3: causal flash attention (LDS-staged) --------------
// 512 blocks x 512 threads (8 waves = 2 q-subtiles x 4-way KV split).
// Block = one 32-row q-tile; longest-first; b = bid&3 pins one batch per XCD.
// LDS: 64KB K/V dbuf, merge buffer oM OVERLAID on it (used only post-loop)
// -> 66.5KB/block -> 2 blocks/CU.
__launch_bounds__(512, 4)
__global__ void attn(const unsigned short* __restrict__ q16, const unsigned short* __restrict__ k16,
                     const unsigned short* __restrict__ vt16, float* __restrict__ out) {
    __shared__ __align__(16) unsigned char lds[2][32768];  // [buf][K 16KB | V 16KB]
    __shared__ float mM[2][4][16], lM[2][4][16];
    float* const oMp = (float*)&lds[0][0];                 // overlay: [sq][sk][16][64]

    const int tid = threadIdx.x;
    const int w = tid >> 6, lane = tid & 63, r = lane & 15, g = lane >> 4;
    const int sq = w >> 2, sk = w & 3;
    const int bid = blockIdx.x;
    const int b = bid & 3;                                 // XCD (bid%8) sees one batch
    const int j = 127 - (bid >> 2);                        // longest tiles dispatched first
    const size_t kbase = (size_t)b * Tn;
    const float scale = 0.125f;

    const int q0 = j * 32;
    const int nIt = (j + 4) >> 2;                          // ceil(32(j+1)/128)
    const int qrow = b * Tn + q0 + sq * 16;
    const int q = q0 + sq * 16 + r;
    const int qmax = q0 + sq * 16 + 15;

    const bf16x8 bq0 = *(const bf16x8*)&q16[(qrow + r) * 64 + g * 8];
    const bf16x8 bq1 = *(const bf16x8*)&q16[(qrow + r) * 64 + 32 + g * 8];

    f32x4 o[4];
#pragma unroll
    for (int i = 0; i < 4; ++i) o[i] = (f32x4){0.f, 0.f, 0.f, 0.f};
    float m_ = -1e30f, l_ = 0.f;

    // prologue: stage kv tile 0 into buf 0
    {
#pragma unroll
        for (int p = 0; p < 2; ++p) {
            int row = p * 64 + (tid >> 3), cb = (tid & 7) * 16;
            bf16x8 t = *(const bf16x8*)((const char*)k16 + (kbase + row) * 128 + cb);
            *(bf16x8*)&lds[0][row * 128 + (cb ^ ((row & 7) << 4))] = t;
        }
#pragma unroll
        for (int p = 0; p < 2; ++p) {
            int h = p * 32 + (tid >> 4), cb = (tid & 15) * 16;
            bf16x8 t = *(const bf16x8*)((const char*)vt16 + ((size_t)(b * 64 + h)) * 8192 + cb);
            *(bf16x8*)&lds[0][16384 + h * 256 + (cb ^ ((h & 7) << 4))] = t;
        }
    }
    __syncthreads();

    for (int it = 0; it < nIt; ++it) {
        const int pp = it & 1;
        const int kv0 = it * 128;
        const bool more = (it + 1 < nIt);
        // T14: issue next-stage global loads early
        bf16x8 sK0, sK1, sV0, sV1;
        int dK0 = 0, dK1 = 0, dV0 = 0, dV1 = 0;
        if (more) {
            int nkv = kv0 + 128;
            int row0_ = (tid >> 3), cb = (tid & 7) * 16;
            sK0 = *(const bf16x8*)((const char*)k16 + (kbase + nkv + row0_) * 128 + cb);
            dK0 = row0_ * 128 + (cb ^ ((row0_ & 7) << 4));
            int row1_ = 64 + row0_;
            sK1 = *(const bf16x8*)((const char*)k16 + (kbase + nkv + row1_) * 128 + cb);
            dK1 = row1_ * 128 + (cb ^ ((row1_ & 7) << 4));
            int h0 = (tid >> 4), cv = (tid & 15) * 16;
            sV0 = *(const bf16x8*)((const char*)vt16 + ((size_t)(b * 64 + h0)) * 8192 + nkv * 2 + cv);
            dV0 = 16384 + h0 * 256 + (cv ^ ((h0 & 7) << 4));
            int h1 = 32 + h0;
            sV1 = *(const bf16x8*)((const char*)vt16 + ((size_t)(b * 64 + h1)) * 8192 + nkv * 2 + cv);
            dV1 = 16384 + h1 * 256 + (cv ^ ((h1 & 7) << 4));
        }
        // compute on buf pp (wave-uniform causal skip; barriers stay outside)
        if (kv0 + sk * 32 <= qmax) {
            const unsigned char* K = &lds[pp][0];
            const unsigned char* V = &lds[pp][16384];
            f32x4 s[2];
#pragma unroll
            for (int ct = 0; ct < 2; ++ct) {
                int row = sk * 32 + ct * 16 + r;
                int base = row * 128, sw = (row & 7) << 4;
                bf16x8 ak0 = *(const bf16x8*)&K[base + ((g * 16) ^ sw)];
                bf16x8 ak1 = *(const bf16x8*)&K[base + ((64 + g * 16) ^ sw)];
                f32x4 t = (f32x4){0.f, 0.f, 0.f, 0.f};
                t = MFMA16(ak0, bq0, t);
                t = MFMA16(ak1, bq1, t);
                s[ct] = t;
            }
#pragma unroll
            for (int ct = 0; ct < 2; ++ct)
#pragma unroll
                for (int reg = 0; reg < 4; ++reg) {
                    int kv = kv0 + sk * 32 + ct * 16 + g * 4 + reg;
                    s[ct][reg] = (kv > q) ? NEGINF : s[ct][reg] * scale;
                }
            // softmax over this 32-kv window (lane owns q-row r)
            float mx = fmaxf(fmaxf(fmaxf(s[0][0], s[0][1]), fmaxf(s[0][2], s[0][3])),
                             fmaxf(fmaxf(s[1][0], s[1][1]), fmaxf(s[1][2], s[1][3])));
            mx = fmaxf(mx, __shfl_xor(mx, 16));
            mx = fmaxf(mx, __shfl_xor(mx, 32));
            float mn = fmaxf(m_, mx);
            float corr = __expf(m_ - mn);
            m_ = mn;
#pragma unroll
            for (int ct = 0; ct < 2; ++ct)
#pragma unroll
                for (int reg = 0; reg < 4; ++reg)
                    s[ct][reg] = __expf(s[ct][reg] - mn);
            float sm = ((s[0][0] + s[0][1]) + (s[0][2] + s[0][3])) +
                       ((s[1][0] + s[1][1]) + (s[1][2] + s[1][3]));
            sm += __shfl_xor(sm, 16);
            sm += __shfl_xor(sm, 32);
            l_ = l_ * corr + sm;
            float cq[4];
#pragma unroll
            for (int reg = 0; reg < 4; ++reg) cq[reg] = __shfl(corr, g * 4 + reg);
#pragma unroll
            for (int cth = 0; cth < 4; ++cth)
#pragma unroll
                for (int reg = 0; reg < 4; ++reg) o[cth][reg] *= cq[reg];
            // pack P: A-slot j -> window-kv = (j>>2)*16 + g*4 + (j&3)
            union { bf16x8 v; unsigned short u[8]; } pk;
#pragma unroll
            for (int jj = 0; jj < 4; ++jj) {
                pk.u[jj] = f2bf(s[0][jj]);
                pk.u[4 + jj] = f2bf(s[1][jj]);
            }
            // PV: V B-frag with same bijection, swizzled reads
#pragma unroll
            for (int cth = 0; cth < 4; ++cth) {
                int h = cth * 16 + r;
                int vb = h * 256, sw = (h & 7) << 4;
                union { bf16x8 v; bf16x4 h4[2]; } vv;
                vv.h4[0] = *(const bf16x4*)&V[vb + ((sk * 64 + g * 8) ^ sw)];
                vv.h4[1] = *(const bf16x4*)&V[vb + ((sk * 64 + 32 + g * 8) ^ sw)];
                o[cth] = MFMA16(pk.v, vv.v, o[cth]);
            }
        }
        if (more) {
            unsigned char* D = &lds[pp ^ 1][0];
            *(bf16x8*)&D[dK0] = sK0;
            *(bf16x8*)&D[dK1] = sK1;
            *(bf16x8*)&D[dV0] = sV0;
            *(bf16x8*)&D[dV1] = sV1;
        }
        __syncthreads();
    }

    // ---- partials to LDS (oM overlays the stage buffers; loop is done) ----
#pragma unroll
    for (int cth = 0; cth < 4; ++cth)
#pragma unroll
        for (int reg = 0; reg < 4; ++reg)
            oMp[(((sq * 4 + sk) * 16) + g * 4 + reg) * 64 + cth * 16 + r] = o[cth][reg];
    if (lane < 16) {
        mM[sq][sk][lane] = m_;
        lM[sq][sk][lane] = l_;
    }
    __syncthreads();

    // ---- merge 4-way across sk; wave (sq,sk) takes rows sk*4+g ----
    {
        int rr = sk * 4 + g;
        float m0 = mM[sq][0][rr], m1 = mM[sq][1][rr], m2 = mM[sq][2][rr], m3 = mM[sq][3][rr];
        float M = fmaxf(fmaxf(m0, m1), fmaxf(m2, m3));
        float w0 = __expf(m0 - M), w1 = __expf(m1 - M), w2 = __expf(m2 - M), w3 = __expf(m3 - M);
        float L = w0 * lM[sq][0][rr] + w1 * lM[sq][1][rr] + w2 * lM[sq][2][rr] + w3 * lM[sq][3][rr];
        float inv = 1.0f / L;
        int orow = b * Tn + q0 + sq * 16 + rr;
        const float* oq = &oMp[(sq * 4) * 16 * 64];
#pragma unroll
        for (int jj = 0; jj < 4; ++jj) {
            int col = r + 16 * jj;
            float val = w0 * oq[(0 * 16 + rr) * 64 + col] + w1 * oq[(1 * 16 + rr) * 64 + col] +
                        w2 * oq[(2 * 16 + rr) * 64 + col] + w3 * oq[(3 * 16 + rr) * 64 + col];
            out[orow * 64 + col] = val * inv;
        }
    }
}

extern "C" void kernel_launch(void* const* d_in, const int* in_sizes, int n_in,
                              void* d_out, int out_size, void* d_ws, size_t ws_size,
                              hipStream_t stream) {
    const float* x  = (const float*)d_in[0];
    const float* Wq = (const float*)d_in[1];
    const float* Wk = (const float*)d_in[2];
    const float* Wv = (const float*)d_in[3];
    float* out = (float*)d_out;
    char* ws = (char*)d_ws;

    unsigned short* Wo  = (unsigned short*)ws;                       // 192*512*2   = 196608 B
    unsigned short* q16 = (unsigned short*)(ws + 196608);            // 16384*64*2  = 2 MiB
    unsigned short* k16 = (unsigned short*)(ws + 196608 + 2097152);
    unsigned short* v16 = (unsigned short*)(ws + 196608 + 2 * 2097152);

    hipLaunchKernelGGL(wcvt, dim3(384), dim3(256), 0, stream, Wq, Wk, Wv, Wo);
    hipLaunchKernelGGL(proj, dim3(256), dim3(256), 0, stream, x, Wo, q16, k16, v16);
    hipLaunchKernelGGL(attn, dim3(512), dim3(512), 0, stream, q16, k16, v16, out);
}

// Round 6
// 68.581 us; speedup vs baseline: 1.9363x; 1.0617x over previous
//
#include <hip/hip_runtime.h>
#include <hip/hip_bf16.h>

// B=4, T=4096, E=512, H=64. out fp32 [B,T,H].
#define Bn 4
#define Tn 4096
#define En 512
#define Hn 64
#define NEGINF -3e38f

typedef __attribute__((ext_vector_type(8))) __bf16 bf16x8;
typedef __attribute__((ext_vector_type(4))) __bf16 bf16x4;
typedef __attribute__((ext_vector_type(4))) float f32x4;

#define MFMA16(a, b, c) __builtin_amdgcn_mfma_f32_16x16x32_bf16(a, b, c, 0, 0, 0)

__device__ __forceinline__ unsigned short f2bf(float f) {
    union { float f; unsigned u; } v; v.f = f;
    unsigned r = v.u + 0x7fffu + ((v.u >> 16) & 1u);
    return (unsigned short)(r >> 16);
}

// ---------------- kernel 1: W fp32 -> bf16 concat [192][512] ----------------
__global__ void wcvt(const float* __restrict__ Wq, const float* __restrict__ Wk,
                     const float* __restrict__ Wv, unsigned short* __restrict__ Wo) {
    int i = blockIdx.x * 256 + threadIdx.x;      // 0..98303
    int mat = i >> 15;                            // each W is 64*512 = 32768
    int off = i & 32767;
    const float* s = (mat == 0) ? Wq : ((mat == 1) ? Wk : Wv);
    Wo[i] = f2bf(s[off]);
}

// ---------------- kernel 2: fused QKV projection (bf16 MFMA GEMM) -----------
// y = x @ Wqkv^T : M=16384 rows, N=192 cols, K=512.
// cols 0-63 -> q[row][h], 64-127 -> k[row][h], 128-191 -> v^T[b][h][t].
__launch_bounds__(256, 2)
__global__ void proj(const float* __restrict__ x, const unsigned short* __restrict__ Wo,
                     unsigned short* __restrict__ q16, unsigned short* __restrict__ k16,
                     unsigned short* __restrict__ vt16) {
    __shared__ unsigned short sA[64 * 72];   // 64 rows x 64 k, stride 72 (pad kills bank conflict)
    __shared__ unsigned short sW[192 * 72];
    const int tid = threadIdx.x;
    const int w = tid >> 6, lane = tid & 63, r = lane & 15, g = lane >> 4;
    const int row0 = blockIdx.x * 64;

    f32x4 acc[12];
#pragma unroll
    for (int i = 0; i < 12; ++i) acc[i] = (f32x4){0.f, 0.f, 0.f, 0.f};

    for (int k0 = 0; k0 < En; k0 += 64) {
#pragma unroll
        for (int i = 0; i < 2; ++i) {
            int c = tid + i * 256; int arow = c >> 3, kc = (c & 7) * 8;
            const float4* xp = (const float4*)&x[(row0 + arow) * En + k0 + kc];
            float4 f0 = xp[0], f1 = xp[1];
            union { bf16x8 v; unsigned short u[8]; } t;
            t.u[0] = f2bf(f0.x); t.u[1] = f2bf(f0.y); t.u[2] = f2bf(f0.z); t.u[3] = f2bf(f0.w);
            t.u[4] = f2bf(f1.x); t.u[5] = f2bf(f1.y); t.u[6] = f2bf(f1.z); t.u[7] = f2bf(f1.w);
            *(bf16x8*)&sA[arow * 72 + kc] = t.v;
        }
#pragma unroll
        for (int i = 0; i < 6; ++i) {
            int c = tid + i * 256; int wrow = c >> 3, kc = (c & 7) * 8;
            bf16x8 wv = *(const bf16x8*)&Wo[wrow * En + k0 + kc];
            *(bf16x8*)&sW[wrow * 72 + kc] = wv;
        }
        __syncthreads();
        bf16x8 a0 = *(bf16x8*)&sA[(w * 16 + r) * 72 + g * 8];
        bf16x8 a1 = *(bf16x8*)&sA[(w * 16 + r) * 72 + 32 + g * 8];
#pragma unroll
        for (int ct = 0; ct < 12; ++ct) {
            bf16x8 b0 = *(bf16x8*)&sW[(ct * 16 + r) * 72 + g * 8];
            bf16x8 b1 = *(bf16x8*)&sW[(ct * 16 + r) * 72 + 32 + g * 8];
            acc[ct] = MFMA16(a0, b0, acc[ct]);
            acc[ct] = MFMA16(a1, b1, acc[ct]);
        }
        __syncthreads();
    }
#pragma unroll
    for (int ct = 0; ct < 12; ++ct) {
        int n = ct * 16 + r;
#pragma unroll
        for (int reg = 0; reg < 4; ++reg) {
            int gr = row0 + w * 16 + g * 4 + reg;
            unsigned short bv = f2bf(acc[ct][reg]);
            if (n < 64) {
                q16[gr * 64 + n] = bv;
            } else if (n < 128) {
                k16[gr * 64 + (n - 64)] = bv;
            } else {
                int h = n - 128; int bb = gr >> 12; int t = gr & 4095;
                vt16[((bb * 64 + h) << 12) + t] = bv;
            }
        }
    }
}

// ---------------- kernel 3: causal flash attention (LDS-staged) --------------
// 512 blocks x 512 threads (8 waves = 2 q-subtiles x 4-way KV split).
// Complementary-j grid: bid<256 -> j=127-(bid>>2); bid>=256 -> j=(bid-256)>>2.
// CU c's two resident blocks have j1+j2=127 -> uniform ~34 iters/CU.
// LDS: 64KB K/V dbuf, merge buffer oM overlaid -> 66.5KB -> 2 blocks/CU.
// Defer-max (THR=8) skips O-rescale in the common case; setprio around MFMA.
__launch_bounds__(512, 4)
__global__ void attn(const unsigned short* __restrict__ q16, const unsigned short* __restrict__ k16,
                     const unsigned short* __restrict__ vt16, float* __restrict__ out) {
    __shared__ __align__(16) unsigned char lds[2][32768];  // [buf][K 16KB | V 16KB]
    __shared__ float mM[2][4][16], lM[2][4][16];
    float* const oMp = (float*)&lds[0][0];                 // overlay: [sq][sk][16][64]

    const int tid = threadIdx.x;
    const int w = tid >> 6, lane = tid & 63, r = lane & 15, g = lane >> 4;
    const int sq = w >> 2, sk = w & 3;
    const int bid = blockIdx.x;
    const int idx = bid & 255;
    const int b = idx & 3;                                 // XCD (bid%8) sees one batch
    const int j = (bid >> 8) ? (idx >> 2) : 127 - (idx >> 2);
    const size_t kbase = (size_t)b * Tn;
    const float scale = 0.125f;

    const int q0 = j * 32;
    const int nIt = (j + 4) >> 2;                          // ceil(32(j+1)/128)
    const int qrow = b * Tn + q0 + sq * 16;
    const int q = q0 + sq * 16 + r;
    const int qmax = q0 + sq * 16 + 15;

    const bf16x8 bq0 = *(const bf16x8*)&q16[(qrow + r) * 64 + g * 8];
    const bf16x8 bq1 = *(const bf16x8*)&q16[(qrow + r) * 64 + 32 + g * 8];

    f32x4 o[4];
#pragma unroll
    for (int i = 0; i < 4; ++i) o[i] = (f32x4){0.f, 0.f, 0.f, 0.f};
    float m_ = -1e30f, l_ = 0.f;

    // prologue: stage kv tile 0 into buf 0
    {
#pragma unroll
        for (int p = 0; p < 2; ++p) {
            int row = p * 64 + (tid >> 3), cb = (tid & 7) * 16;
            bf16x8 t = *(const bf16x8*)((const char*)k16 + (kbase + row) * 128 + cb);
            *(bf16x8*)&lds[0][row * 128 + (cb ^ ((row & 7) << 4))] = t;
        }
#pragma unroll
        for (int p = 0; p < 2; ++p) {
            int h = p * 32 + (tid >> 4), cb = (tid & 15) * 16;
            bf16x8 t = *(const bf16x8*)((const char*)vt16 + ((size_t)(b * 64 + h)) * 8192 + cb);
            *(bf16x8*)&lds[0][16384 + h * 256 + (cb ^ ((h & 7) << 4))] = t;
        }
    }
    __syncthreads();

    for (int it = 0; it < nIt; ++it) {
        const int pp = it & 1;
        const int kv0 = it * 128;
        const bool more = (it + 1 < nIt);
        // T14: issue next-stage global loads early
        bf16x8 sK0, sK1, sV0, sV1;
        int dK0 = 0, dK1 = 0, dV0 = 0, dV1 = 0;
        if (more) {
            int nkv = kv0 + 128;
            int row0_ = (tid >> 3), cb = (tid & 7) * 16;
            sK0 = *(const bf16x8*)((const char*)k16 + (kbase + nkv + row0_) * 128 + cb);
            dK0 = row0_ * 128 + (cb ^ ((row0_ & 7) << 4));
            int row1_ = 64 + row0_;
            sK1 = *(const bf16x8*)((const char*)k16 + (kbase + nkv + row1_) * 128 + cb);
            dK1 = row1_ * 128 + (cb ^ ((row1_ & 7) << 4));
            int h0 = (tid >> 4), cv = (tid & 15) * 16;
            sV0 = *(const bf16x8*)((const char*)vt16 + ((size_t)(b * 64 + h0)) * 8192 + nkv * 2 + cv);
            dV0 = 16384 + h0 * 256 + (cv ^ ((h0 & 7) << 4));
            int h1 = 32 + h0;
            sV1 = *(const bf16x8*)((const char*)vt16 + ((size_t)(b * 64 + h1)) * 8192 + nkv * 2 + cv);
            dV1 = 16384 + h1 * 256 + (cv ^ ((h1 & 7) << 4));
        }
        // compute on buf pp (wave-uniform causal skip; barriers stay outside)
        if (kv0 + sk * 32 <= qmax) {
            const unsigned char* K = &lds[pp][0];
            const unsigned char* V = &lds[pp][16384];
            f32x4 s[2];
            __builtin_amdgcn_s_setprio(1);
#pragma unroll
            for (int ct = 0; ct < 2; ++ct) {
                int row = sk * 32 + ct * 16 + r;
                int base = row * 128, sw = (row & 7) << 4;
                bf16x8 ak0 = *(const bf16x8*)&K[base + ((g * 16) ^ sw)];
                bf16x8 ak1 = *(const bf16x8*)&K[base + ((64 + g * 16) ^ sw)];
                f32x4 t = (f32x4){0.f, 0.f, 0.f, 0.f};
                t = MFMA16(ak0, bq0, t);
                t = MFMA16(ak1, bq1, t);
                s[ct] = t;
            }
            __builtin_amdgcn_s_setprio(0);
#pragma unroll
            for (int ct = 0; ct < 2; ++ct)
#pragma unroll
                for (int reg = 0; reg < 4; ++reg) {
                    int kv = kv0 + sk * 32 + ct * 16 + g * 4 + reg;
                    s[ct][reg] = (kv > q) ? NEGINF : s[ct][reg] * scale;
                }
            // row max over this 32-kv window (lane owns q-row r)
            float mx = fmaxf(fmaxf(fmaxf(s[0][0], s[0][1]), fmaxf(s[0][2], s[0][3])),
                             fmaxf(fmaxf(s[1][0], s[1][1]), fmaxf(s[1][2], s[1][3])));
            mx = fmaxf(mx, __shfl_xor(mx, 16));
            mx = fmaxf(mx, __shfl_xor(mx, 32));
            // defer-max: only rescale when the max grew by > 8
            if (__any(mx > m_ + 8.0f)) {
                float mn = fmaxf(m_, mx);
                float corr = __expf(m_ - mn);
                m_ = mn;
                l_ *= corr;
                float cq[4];
#pragma unroll
                for (int reg = 0; reg < 4; ++reg) cq[reg] = __shfl(corr, g * 4 + reg);
#pragma unroll
                for (int cth = 0; cth < 4; ++cth)
#pragma unroll
                    for (int reg = 0; reg < 4; ++reg) o[cth][reg] *= cq[reg];
            }
#pragma unroll
            for (int ct = 0; ct < 2; ++ct)
#pragma unroll
                for (int reg = 0; reg < 4; ++reg)
                    s[ct][reg] = __expf(s[ct][reg] - m_);
            float sm = ((s[0][0] + s[0][1]) + (s[0][2] + s[0][3])) +
                       ((s[1][0] + s[1][1]) + (s[1][2] + s[1][3]));
            sm += __shfl_xor(sm, 16);
            sm += __shfl_xor(sm, 32);
            l_ += sm;
            // pack P: A-slot j -> window-kv = (j>>2)*16 + g*4 + (j&3)
            union { bf16x8 v; unsigned short u[8]; } pk;
#pragma unroll
            for (int jj = 0; jj < 4; ++jj) {
                pk.u[jj] = f2bf(s[0][jj]);
                pk.u[4 + jj] = f2bf(s[1][jj]);
            }
            // PV: V B-frag with same bijection, swizzled reads
            __builtin_amdgcn_s_setprio(1);
#pragma unroll
            for (int cth = 0; cth < 4; ++cth) {
                int h = cth * 16 + r;
                int vb = h * 256, sw = (h & 7) << 4;
                union { bf16x8 v; bf16x4 h4[2]; } vv;
                vv.h4[0] = *(const bf16x4*)&V[vb + ((sk * 64 + g * 8) ^ sw)];
                vv.h4[1] = *(const bf16x4*)&V[vb + ((sk * 64 + 32 + g * 8) ^ sw)];
                o[cth] = MFMA16(pk.v, vv.v, o[cth]);
            }
            __builtin_amdgcn_s_setprio(0);
        }
        if (more) {
            unsigned char* D = &lds[pp ^ 1][0];
            *(bf16x8*)&D[dK0] = sK0;
            *(bf16x8*)&D[dK1] = sK1;
            *(bf16x8*)&D[dV0] = sV0;
            *(bf16x8*)&D[dV1] = sV1;
        }
        __syncthreads();
    }

    // ---- partials to LDS (oM overlays the stage buffers; loop is done) ----
#pragma unroll
    for (int cth = 0; cth < 4; ++cth)
#pragma unroll
        for (int reg = 0; reg < 4; ++reg)
            oMp[(((sq * 4 + sk) * 16) + g * 4 + reg) * 64 + cth * 16 + r] = o[cth][reg];
    if (lane < 16) {
        mM[sq][sk][lane] = m_;
        lM[sq][sk][lane] = l_;
    }
    __syncthreads();

    // ---- merge 4-way across sk; wave (sq,sk) takes rows sk*4+g ----
    {
        int rr = sk * 4 + g;
        float m0 = mM[sq][0][rr], m1 = mM[sq][1][rr], m2 = mM[sq][2][rr], m3 = mM[sq][3][rr];
        float M = fmaxf(fmaxf(m0, m1), fmaxf(m2, m3));
        float w0 = __expf(m0 - M), w1 = __expf(m1 - M), w2 = __expf(m2 - M), w3 = __expf(m3 - M);
        float L = w0 * lM[sq][0][rr] + w1 * lM[sq][1][rr] + w2 * lM[sq][2][rr] + w3 * lM[sq][3][rr];
        float inv = 1.0f / L;
        int orow = b * Tn + q0 + sq * 16 + rr;
        const float* oq = &oMp[(sq * 4) * 16 * 64];
#pragma unroll
        for (int jj = 0; jj < 4; ++jj) {
            int col = r + 16 * jj;
            float val = w0 * oq[(0 * 16 + rr) * 64 + col] + w1 * oq[(1 * 16 + rr) * 64 + col] +
                        w2 * oq[(2 * 16 + rr) * 64 + col] + w3 * oq[(3 * 16 + rr) * 64 + col];
            out[orow * 64 + col] = val * inv;
        }
    }
}

extern "C" void kernel_launch(void* const* d_in, const int* in_sizes, int n_in,
                              void* d_out, int out_size, void* d_ws, size_t ws_size,
                              hipStream_t stream) {
    const float* x  = (const float*)d_in[0];
    const float* Wq = (const float*)d_in[1];
    const float* Wk = (const float*)d_in[2];
    const float* Wv = (const float*)d_in[3];
    float* out = (float*)d_out;
    char* ws = (char*)d_ws;

    unsigned short* Wo  = (unsigned short*)ws;                       // 192*512*2   = 196608 B
    unsigned short* q16 = (unsigned short*)(ws + 196608);            // 16384*64*2  = 2 MiB
    unsigned short* k16 = (unsigned short*)(ws + 196608 + 2097152);
    unsigned short* v16 = (unsigned short*)(ws + 196608 + 2 * 2097152);

    hipLaunchKernelGGL(wcvt, dim3(384), dim3(256), 0, stream, Wq, Wk, Wv, Wo);
    hipLaunchKernelGGL(proj, dim3(256), dim3(256), 0, stream, x, Wo, q16, k16, v16);
    hipLaunchKernelGGL(attn, dim3(512), dim3(512), 0, stream, q16, k16, v16, out);
}